// Round 1
// baseline (82.548 us; speedup 1.0000x reference)
//
#include <hip/hip_runtime.h>
#include <math.h>

#define NB 64
#define NL 3168
#define NC 64
#define ND 512
#define NK 16
#define NW 198
#define NM 12672   // NB*NW rows
#define KD 1024    // NC*NK contraction dim, flattened as k*64+c
#define LDT 72     // padded LDS stride in shorts (144B) -> 2-way bank conflict only

typedef __attribute__((ext_vector_type(8))) short bf8_t;   // 8 bf16 (4 VGPR) MFMA A/B frag
typedef __attribute__((ext_vector_type(4))) float f4_t;    // MFMA C/D frag

__device__ __forceinline__ unsigned short f2bf(float f) {
  union { float f; unsigned u; } v; v.f = f;
  unsigned r = v.u + 0x7FFFu + ((v.u >> 16) & 1u);
  return (unsigned short)(r >> 16);
}

// ---------------------------------------------------------------------------
// prep: wdeft[d][k*64+c] = w_def[d][c][k] (bf16); wofft[o][k*64+c] = w_off[o][c][k];
//       pe[pos][d] table (f32); cls rows of output (pe[0][d] = d odd ? 1 : 0)
// ---------------------------------------------------------------------------
__global__ void prep_kernel(const float* __restrict__ w_off, const float* __restrict__ w_def,
                            const float* __restrict__ cls, unsigned short* __restrict__ wofft,
                            unsigned short* __restrict__ wdeft, float* __restrict__ pe,
                            float* __restrict__ out) {
  int id = blockIdx.x * 256 + threadIdx.x;
  if (id < 524288) {
    int d = id >> 10, kc = id & 1023, k = kc >> 6, c = kc & 63;
    wdeft[id] = f2bf(w_def[d * 1024 + c * 16 + k]);
    return;
  }
  id -= 524288;
  if (id < 32768) {
    int o = id >> 10, kc = id & 1023, k = kc >> 6, c = kc & 63;
    wofft[id] = f2bf(w_off[o * 1024 + c * 16 + k]);
    return;
  }
  id -= 32768;
  if (id < 101888) {   // 199 * 512 positional-encoding table
    int pos = id >> 9, d = id & 511;
    int i = d >> 1;
    float freq = expf((float)(2 * i) * (-9.210340371976184f / 512.0f));
    float arg = (float)pos * freq;
    pe[id] = (d & 1) ? cosf(arg) : sinf(arg);
    return;
  }
  id -= 101888;
  {  // 64 * 512 cls-token rows: out[b][0][d] = cls[d] + pe[0][d]
    int b = id >> 9, d = id & 511;
    out[(size_t)(b * 199) * 512 + d] = cls[d] + ((d & 1) ? 1.0f : 0.0f);
  }
}

// ---------------------------------------------------------------------------
// off GEMM: off_ws[row][o] = sum_kc x[row][kc] * wofft[o][kc] + b_off[o]
// 99 blocks x 256 thr; BM=128, BN=32, BK=64; A reg-staged f32->bf16
// ---------------------------------------------------------------------------
__launch_bounds__(256)
__global__ void offgemm_kernel(const float* __restrict__ x, const unsigned short* __restrict__ wofft,
                               const float* __restrict__ b_off, float* __restrict__ off_ws) {
  __shared__ unsigned short As[128 * LDT];
  __shared__ unsigned short Bs[32 * LDT];
  int tid = threadIdx.x;
  int blk = blockIdx.x;
  int lane = tid & 63, wid = tid >> 6;
  int r16 = lane & 15, kg = lane >> 4;
  f4_t acc[2][2] = {};

  int arow = tid >> 1, ahalf = tid & 1;
  const float* asrc_base = x + (size_t)(blk * 128 + arow) * KD + ahalf * 32;
  unsigned short* adst = &As[arow * LDT + ahalf * 32];
  int brow = tid >> 3, bk = (tid & 7) * 8;
  const unsigned short* bsrc_base = wofft + brow * KD + bk;
  unsigned short* bdst = &Bs[brow * LDT + bk];

  for (int ks = 0; ks < 16; ++ks) {
    int k0 = ks * 64;
    __syncthreads();
    // stage A: 32 f32 -> 32 bf16 per thread
    __attribute__((aligned(16))) unsigned short tmp[32];
    const float* asrc = asrc_base + k0;
#pragma unroll
    for (int i = 0; i < 8; ++i) {
      float4 v = *(const float4*)(asrc + i * 4);
      tmp[i * 4 + 0] = f2bf(v.x); tmp[i * 4 + 1] = f2bf(v.y);
      tmp[i * 4 + 2] = f2bf(v.z); tmp[i * 4 + 3] = f2bf(v.w);
    }
#pragma unroll
    for (int i = 0; i < 4; ++i) ((uint4*)adst)[i] = ((const uint4*)tmp)[i];
    // stage B: 4KB
    *(uint4*)bdst = *(const uint4*)(bsrc_base + k0);
    __syncthreads();
#pragma unroll
    for (int kk = 0; kk < 64; kk += 32) {
      bf8_t a0 = *(const bf8_t*)&As[(wid * 32 + r16) * LDT + kk + kg * 8];
      bf8_t a1 = *(const bf8_t*)&As[(wid * 32 + 16 + r16) * LDT + kk + kg * 8];
      bf8_t b0 = *(const bf8_t*)&Bs[r16 * LDT + kk + kg * 8];
      bf8_t b1 = *(const bf8_t*)&Bs[(16 + r16) * LDT + kk + kg * 8];
      acc[0][0] = __builtin_amdgcn_mfma_f32_16x16x32_bf16(a0, b0, acc[0][0], 0, 0, 0);
      acc[0][1] = __builtin_amdgcn_mfma_f32_16x16x32_bf16(a0, b1, acc[0][1], 0, 0, 0);
      acc[1][0] = __builtin_amdgcn_mfma_f32_16x16x32_bf16(a1, b0, acc[1][0], 0, 0, 0);
      acc[1][1] = __builtin_amdgcn_mfma_f32_16x16x32_bf16(a1, b1, acc[1][1], 0, 0, 0);
    }
  }
#pragma unroll
  for (int m = 0; m < 2; ++m)
#pragma unroll
    for (int n = 0; n < 2; ++n)
#pragma unroll
      for (int r = 0; r < 4; ++r) {
        int grow = blk * 128 + wid * 32 + m * 16 + kg * 4 + r;
        int o = n * 16 + r16;
        off_ws[grow * 32 + o] = acc[m][n][r] + b_off[o];
      }
}

// ---------------------------------------------------------------------------
// sampling: val_ws[row][k*64+c] = wy * ((1-frac)*v0 + frac*v1)  (bf16)
// one wave per row; lane = channel c
// ---------------------------------------------------------------------------
__global__ void sample_kernel(const float* __restrict__ x, const float* __restrict__ off_ws,
                              unsigned short* __restrict__ val_ws) {
  int tid = threadIdx.x;
  int wid = tid >> 6, lane = tid & 63;
  int row = blockIdx.x * 4 + wid;
  int b = row / 198, w = row - b * 198;
  const float* xb = x + (size_t)b * NL * NC;
  const float* offr = off_ws + row * 32;
  unsigned short* dst = val_ws + (size_t)row * KD;
#pragma unroll
  for (int k = 0; k < 16; ++k) {
    float dy = offr[2 * k], dx = offr[2 * k + 1];
    float wy = fmaxf(0.f, 1.f - fabsf(dy));
    float px = (float)(w * 16 + k) + dx;
    float x0f = floorf(px);
    float frac = px - x0f;
    int x0 = (int)x0f;
    float v0 = (x0 >= 0 && x0 < NL) ? xb[x0 * 64 + lane] : 0.f;
    float v1 = (x0 + 1 >= 0 && x0 + 1 < NL) ? xb[(x0 + 1) * 64 + lane] : 0.f;
    float val = wy * ((1.f - frac) * v0 + frac * v1);
    dst[k * 64 + lane] = f2bf(val);
  }
}

// ---------------------------------------------------------------------------
// main GEMM: out[b*199 + w + 1][d] = sum_kc val[row][kc]*wdeft[d][kc] + b_def[d] + pe[w+1][d]
// grid (99, 4); BM=BN=128, BK=64; 4 waves 2x2, each 64x64
// ---------------------------------------------------------------------------
__launch_bounds__(256)
__global__ void gemm_kernel(const unsigned short* __restrict__ val_ws,
                            const unsigned short* __restrict__ wdeft,
                            const float* __restrict__ b_def, const float* __restrict__ pe,
                            float* __restrict__ out) {
  __shared__ unsigned short As[128 * LDT];
  __shared__ unsigned short Bs[128 * LDT];
  int tid = threadIdx.x;
  int mt = blockIdx.x, nt = blockIdx.y;
  int lane = tid & 63, wid = tid >> 6;
  int r16 = lane & 15, kg = lane >> 4;
  int wr = wid >> 1, wc = wid & 1;
  f4_t acc[4][4] = {};

  int srow = tid >> 1, shalf = tid & 1;
  const unsigned short* asrc = val_ws + (size_t)(mt * 128 + srow) * KD + shalf * 32;
  const unsigned short* bsrc = wdeft + (size_t)(nt * 128 + srow) * KD + shalf * 32;
  unsigned short* adst = &As[srow * LDT + shalf * 32];
  unsigned short* bdst = &Bs[srow * LDT + shalf * 32];

  for (int ks = 0; ks < 16; ++ks) {
    int k0 = ks * 64;
    __syncthreads();
#pragma unroll
    for (int i = 0; i < 4; ++i) ((uint4*)adst)[i] = ((const uint4*)(asrc + k0))[i];
#pragma unroll
    for (int i = 0; i < 4; ++i) ((uint4*)bdst)[i] = ((const uint4*)(bsrc + k0))[i];
    __syncthreads();
#pragma unroll
    for (int kk = 0; kk < 64; kk += 32) {
      bf8_t af[4], bff[4];
#pragma unroll
      for (int m = 0; m < 4; ++m)
        af[m] = *(const bf8_t*)&As[(wr * 64 + m * 16 + r16) * LDT + kk + kg * 8];
#pragma unroll
      for (int n = 0; n < 4; ++n)
        bff[n] = *(const bf8_t*)&Bs[(wc * 64 + n * 16 + r16) * LDT + kk + kg * 8];
#pragma unroll
      for (int m = 0; m < 4; ++m)
#pragma unroll
        for (int n = 0; n < 4; ++n)
          acc[m][n] = __builtin_amdgcn_mfma_f32_16x16x32_bf16(af[m], bff[n], acc[m][n], 0, 0, 0);
    }
  }
#pragma unroll
  for (int m = 0; m < 4; ++m)
#pragma unroll
    for (int n = 0; n < 4; ++n)
#pragma unroll
      for (int r = 0; r < 4; ++r) {
        int grow = mt * 128 + wr * 64 + m * 16 + kg * 4 + r;
        int gcol = nt * 128 + wc * 64 + n * 16 + r16;
        int bi = grow / 198, wi = grow - bi * 198;
        out[((size_t)(bi * 199 + wi + 1)) * 512 + gcol] =
            acc[m][n][r] + b_def[gcol] + pe[(wi + 1) * 512 + gcol];
      }
}

extern "C" void kernel_launch(void* const* d_in, const int* in_sizes, int n_in,
                              void* d_out, int out_size, void* d_ws, size_t ws_size,
                              hipStream_t stream) {
  const float* x     = (const float*)d_in[0];
  const float* w_off = (const float*)d_in[1];
  const float* b_off = (const float*)d_in[2];
  const float* w_def = (const float*)d_in[3];
  const float* b_def = (const float*)d_in[4];
  const float* cls   = (const float*)d_in[5];
  float* out = (float*)d_out;
  char* ws = (char*)d_ws;
  // workspace layout (bytes):
  float* off_ws          = (float*)ws;                           // 12672*32*4   = 1,622,016
  unsigned short* val_ws = (unsigned short*)(ws + 2097152);      // 12672*1024*2 = 25,952,256
  unsigned short* wofft  = (unsigned short*)(ws + 28049408);     // 32*1024*2    = 65,536
  unsigned short* wdeft  = (unsigned short*)(ws + 28114944);     // 512*1024*2   = 1,048,576
  float* pe              = (float*)(ws + 29163520);              // 199*512*4    = 407,552  (end 29,571,072)

  prep_kernel<<<2702, 256, 0, stream>>>(w_off, w_def, cls, wofft, wdeft, pe, out);
  offgemm_kernel<<<99, 256, 0, stream>>>(x, wofft, b_off, off_ws);
  sample_kernel<<<3168, 256, 0, stream>>>(x, off_ws, val_ws);
  gemm_kernel<<<dim3(99, 4), 256, 0, stream>>>(val_ws, wdeft, b_def, pe, out);
}